// Round 3
// baseline (629.769 us; speedup 1.0000x reference)
//
#include <hip/hip_runtime.h>
#include <hip/hip_fp16.h>
#include <math.h>

#define D 64
#define RB 1024          // nodes per range (must match >>10 / &1023 below)
#define EB 2048          // edges per partition block
#define NRMAX 128        // static LDS sizing; NR = ceil(N/RB) must be <= NRMAX
#define KHOPS 10

// ---- helpers ------------------------------------------------------------

typedef union { uint4 u; __half2 h[4]; } U4H;

// ---- multisplit CSR build (no global atomics anywhere) ------------------

__global__ void countA(const int* __restrict__ dst, int* __restrict__ countsA_T,
                       int E, int NR, int NBLK) {
    __shared__ int hist[NRMAX];
    int t = threadIdx.x;
    for (int i = t; i < NR; i += 256) hist[i] = 0;
    __syncthreads();
    int base = blockIdx.x * EB + t;
    #pragma unroll
    for (int j = 0; j < EB / 256; ++j) {
        int e = base + j * 256;
        if (e < E) atomicAdd(&hist[dst[e] >> 10], 1);
    }
    __syncthreads();
    for (int i = t; i < NR; i += 256) countsA_T[i * NBLK + blockIdx.x] = hist[i];
}

__global__ void block_sums(const int* __restrict__ arr, int* __restrict__ bsum, int n) {
    int base = blockIdx.x * 1024;
    int t = threadIdx.x;
    int v = 0;
    #pragma unroll
    for (int j = 0; j < 4; ++j) {
        int i = base + t + j * 256;
        if (i < n) v += arr[i];
    }
    #pragma unroll
    for (int m = 32; m >= 1; m >>= 1) v += __shfl_xor(v, m, 64);
    __shared__ int ws[4];
    if ((t & 63) == 0) ws[t >> 6] = v;
    __syncthreads();
    if (t == 0) bsum[blockIdx.x] = ws[0] + ws[1] + ws[2] + ws[3];
}

__global__ void scan_bsums(int* __restrict__ bsum, int nb) {
    __shared__ int tmp[1024];
    int t = threadIdx.x;
    int v = (t < nb) ? bsum[t] : 0;
    tmp[t] = v;
    __syncthreads();
    for (int off = 1; off < 1024; off <<= 1) {
        int x = (t >= off) ? tmp[t - off] : 0;
        __syncthreads();
        tmp[t] += x;
        __syncthreads();
    }
    if (t < nb) bsum[t] = tmp[t] - v;
}

__global__ void gen_scan2(const int* __restrict__ arr, const int* __restrict__ bsum,
                          int* __restrict__ out, int n) {
    __shared__ int tmp[1024];
    int base = blockIdx.x * 1024;
    int t = threadIdx.x;
    int i = base + t;
    int v = (i < n) ? arr[i] : 0;
    tmp[t] = v;
    __syncthreads();
    for (int off = 1; off < 1024; off <<= 1) {
        int x = (t >= off) ? tmp[t - off] : 0;
        __syncthreads();
        tmp[t] += x;
        __syncthreads();
    }
    if (i < n) out[i] = bsum[blockIdx.x] + tmp[t] - v;
}

__global__ void passA2(const int* __restrict__ src, const int* __restrict__ dst,
                       const int* __restrict__ baseA, unsigned int* __restrict__ ebuf2,
                       int E, int NR, int NBLK) {
    __shared__ int cur[NRMAX];
    int t = threadIdx.x;
    for (int i = t; i < NR; i += 256) cur[i] = baseA[i * NBLK + blockIdx.x];
    __syncthreads();
    int base = blockIdx.x * EB + t;
    #pragma unroll
    for (int j = 0; j < EB / 256; ++j) {
        int e = base + j * 256;
        if (e < E) {
            int v = dst[e];
            int pos = atomicAdd(&cur[v >> 10], 1);
            ebuf2[pos] = (unsigned int)src[e] | ((unsigned int)(v & (RB - 1)) << 17);
        }
    }
}

__global__ void range_build(const unsigned int* __restrict__ ebuf2,
                            const int* __restrict__ baseA,
                            int* __restrict__ offsets, float* __restrict__ norm,
                            int* __restrict__ csr, int N, int E, int NR, int NBLK) {
    __shared__ int cnt[RB];
    __shared__ int sc[RB];
    int rg = blockIdx.x;
    int t = threadIdx.x;
    int r0 = baseA[rg * NBLK];
    int r1 = (rg + 1 < NR) ? baseA[(rg + 1) * NBLK] : E;
    cnt[t] = 0;
    __syncthreads();
    for (int i = r0 + t; i < r1; i += RB)
        atomicAdd(&cnt[ebuf2[i] >> 17], 1);
    __syncthreads();
    int v = cnt[t];
    sc[t] = v;
    __syncthreads();
    for (int off = 1; off < RB; off <<= 1) {
        int x = (t >= off) ? sc[t - off] : 0;
        __syncthreads();
        sc[t] += x;
        __syncthreads();
    }
    int excl = sc[t] - v;
    int node = rg * RB + t;
    if (node < N) {
        offsets[node] = r0 + excl;
        norm[node] = rsqrtf((float)(v > 1 ? v : 1));
    }
    if (rg == NR - 1 && t == 0) offsets[N] = E;
    __syncthreads();
    cnt[t] = r0 + excl;
    __syncthreads();
    for (int i = r0 + t; i < r1; i += RB) {
        unsigned int u = ebuf2[i];
        int pos = atomicAdd(&cnt[u >> 17], 1);
        csr[pos] = (int)(u & 0x1FFFFu);
    }
}

// ---- hop 0: g0 = f16(f*norm); if do_pool also out = sigmoid(f.s)*f ------
// 8 lanes per node, 8 dims (2 float4) per lane. Row N of g0 is the shared
// all-zero pad row that lets spmm_hop gather without per-lane masking.
// GRID MUST COVER (N+1)*8 THREADS so the pad row actually gets zeroed.

__global__ void hop0(const float4* __restrict__ feat, const float* __restrict__ s,
                     const float* __restrict__ norm, uint4* __restrict__ g0,
                     float4* __restrict__ out, int n, int do_pool) {
    int t = blockIdx.x * blockDim.x + threadIdx.x;
    int node = t >> 3;
    int l = t & 7;
    if (node > n) return;
    if (node == n) {                           // zero pad row
        g0[(size_t)n * 8 + l] = make_uint4(0u, 0u, 0u, 0u);
        return;
    }
    float4 f0 = feat[node * 16 + 2 * l];
    float4 f1 = feat[node * 16 + 2 * l + 1];
    float nv = norm[node];
    U4H P;
    P.h[0] = __floats2half2_rn(f0.x * nv, f0.y * nv);
    P.h[1] = __floats2half2_rn(f0.z * nv, f0.w * nv);
    P.h[2] = __floats2half2_rn(f1.x * nv, f1.y * nv);
    P.h[3] = __floats2half2_rn(f1.z * nv, f1.w * nv);
    g0[(size_t)node * 8 + l] = P.u;
    if (do_pool) {
        const float4* s4 = (const float4*)s;
        float4 a = s4[2 * l], b = s4[2 * l + 1];
        float dot = f0.x * a.x + f0.y * a.y + f0.z * a.z + f0.w * a.w
                  + f1.x * b.x + f1.y * b.y + f1.z * b.z + f1.w * b.w;
        #pragma unroll
        for (int m = 1; m <= 4; m <<= 1) dot += __shfl_xor(dot, m, 64);
        float sig = 1.0f / (1.0f + expf(-dot));
        out[node * 16 + 2 * l]     = make_float4(sig * f0.x, sig * f0.y, sig * f0.z, sig * f0.w);
        out[node * 16 + 2 * l + 1] = make_float4(sig * f1.x, sig * f1.y, sig * f1.z, sig * f1.w);
    }
}

// ---- hop t: gather-SpMM, 4 nodes per wave for 4x memory-level parallelism
// wave = 64 lanes, lane = 8*g + l; wave owns nodes nb..nb+3. Two packed csr
// loads fetch 32 edge indices for two nodes each (lanes 0-31 / 32-63). All
// gather loads (up to 16, avg ~10) are issued before any accumulate so the
// whole set is in flight together -- attacks the measured latency bound
// (41 us with no pipe >35% busy). Invalid slots gather the all-zero pad row
// n (exact +0 in f16, bit-identical). deg>32 tail handled in f32 (rare:
// P(deg>32) ~ 3e-5 at Poisson(16)).

#define ACCUM_NODE(K, BUF, ACC)                                               \
    {                                                                         \
        __half2 h0 = z, h1 = z, h2 = z, h3 = z;                               \
        if (nr[K] > 0) { h0 = __hadd2(h0, BUF[0].h[0]); h1 = __hadd2(h1, BUF[0].h[1]); h2 = __hadd2(h2, BUF[0].h[2]); h3 = __hadd2(h3, BUF[0].h[3]); } \
        if (nr[K] > 1) { h0 = __hadd2(h0, BUF[1].h[0]); h1 = __hadd2(h1, BUF[1].h[1]); h2 = __hadd2(h2, BUF[1].h[2]); h3 = __hadd2(h3, BUF[1].h[3]); } \
        if (nr[K] > 2) { h0 = __hadd2(h0, BUF[2].h[0]); h1 = __hadd2(h1, BUF[2].h[1]); h2 = __hadd2(h2, BUF[2].h[2]); h3 = __hadd2(h3, BUF[2].h[3]); } \
        if (nr[K] > 3) { h0 = __hadd2(h0, BUF[3].h[0]); h1 = __hadd2(h1, BUF[3].h[1]); h2 = __hadd2(h2, BUF[3].h[2]); h3 = __hadd2(h3, BUF[3].h[3]); } \
        float2 q0 = __half22float2(h0), q1 = __half22float2(h1);              \
        float2 q2 = __half22float2(h2), q3 = __half22float2(h3);              \
        ACC[0] = q0.x; ACC[1] = q0.y; ACC[2] = q1.x; ACC[3] = q1.y;           \
        ACC[4] = q2.x; ACC[5] = q2.y; ACC[6] = q3.x; ACC[7] = q3.y;           \
        for (int i = beg[K] + 32 + g; i < beg[K] + deg[K]; i += 8) {          \
            U4H P; P.u = gin[(size_t)csr[i] * 8 + l];                         \
            float2 b0 = __half22float2(P.h[0]), b1 = __half22float2(P.h[1]);  \
            float2 b2 = __half22float2(P.h[2]), b3 = __half22float2(P.h[3]);  \
            ACC[0] += b0.x; ACC[1] += b0.y; ACC[2] += b1.x; ACC[3] += b1.y;   \
            ACC[4] += b2.x; ACC[5] += b2.y; ACC[6] += b3.x; ACC[7] += b3.y;   \
        }                                                                     \
    }

#define STORE_NODE(K, ACC)                                                    \
    {                                                                         \
        int nd = nb + K;                                                      \
        if (nd < n) {                                                         \
            float nv = norm[nd];                                              \
            float h0 = ACC[0] * nv, h1 = ACC[1] * nv, h2 = ACC[2] * nv, h3 = ACC[3] * nv; \
            float h4 = ACC[4] * nv, h5 = ACC[5] * nv, h6 = ACC[6] * nv, h7 = ACC[7] * nv; \
            float sig = 0.f;                                                  \
            if (do_pool) {                                                    \
                float dot = h0 * sa.x + h1 * sa.y + h2 * sa.z + h3 * sa.w     \
                          + h4 * sb.x + h5 * sb.y + h6 * sb.z + h7 * sb.w;    \
                _Pragma("unroll")                                             \
                for (int m = 1; m <= 4; m <<= 1) dot += __shfl_xor(dot, m, 64); \
                sig = 1.0f / (1.0f + expf(-dot));                             \
            }                                                                 \
            if (g == 0) {                                                     \
                if (write_g) {                                                \
                    U4H P;                                                    \
                    P.h[0] = __floats2half2_rn(h0 * nv, h1 * nv);             \
                    P.h[1] = __floats2half2_rn(h2 * nv, h3 * nv);             \
                    P.h[2] = __floats2half2_rn(h4 * nv, h5 * nv);             \
                    P.h[3] = __floats2half2_rn(h6 * nv, h7 * nv);             \
                    gout[(size_t)nd * 8 + l] = P.u;                           \
                }                                                             \
                if (do_pool) {                                                \
                    float4 o0 = out[nd * 16 + 2 * l];                         \
                    float4 o1 = out[nd * 16 + 2 * l + 1];                     \
                    o0.x += sig * h0; o0.y += sig * h1; o0.z += sig * h2; o0.w += sig * h3; \
                    o1.x += sig * h4; o1.y += sig * h5; o1.z += sig * h6; o1.w += sig * h7; \
                    out[nd * 16 + 2 * l]     = o0;                            \
                    out[nd * 16 + 2 * l + 1] = o1;                            \
                }                                                             \
            }                                                                 \
        } else if (nd == n && write_g && g == 0) {                            \
            gout[(size_t)n * 8 + l] = make_uint4(0u, 0u, 0u, 0u);             \
        }                                                                     \
    }

__global__ __launch_bounds__(256, 4)
void spmm_hop(const uint4* __restrict__ gin, const int* __restrict__ offsets,
              const int* __restrict__ csr, const float* __restrict__ norm,
              const float* __restrict__ s, uint4* __restrict__ gout,
              float4* __restrict__ out, int n, int do_pool, int write_g) {
    int lane = threadIdx.x & 63;
    int wv = threadIdx.x >> 6;
    int nb = __builtin_amdgcn_readfirstlane((int)blockIdx.x * 16 + wv * 4);
    if (nb > n) return;              // wave-uniform exit
    int g = lane >> 3;
    int l = lane & 7;

    // per-node scalars (node ids wave-uniform -> s_loads)
    int beg[4], deg[4], nr[4];
    #pragma unroll
    for (int k = 0; k < 4; ++k) {
        int nd = nb + k;
        int b = 0, e = 0;
        if (nd < n) { b = offsets[nd]; e = offsets[nd + 1]; }
        beg[k] = b;
        deg[k] = e - b;
        int dc = deg[k] < 32 ? deg[k] : 32;
        nr[k] = (dc + 7) >> 3;
    }

    // packed csr index loads: lanes 0-31 -> node {0|2}, lanes 32-63 -> node {1|3}
    int e31 = lane & 31;
    int hi = lane >> 5;
    int bA = hi ? beg[1] : beg[0];
    int cA = hi ? (deg[1] < 32 ? deg[1] : 32) : (deg[0] < 32 ? deg[0] : 32);
    int idxA = (e31 < cA) ? csr[bA + e31] : n;
    int bB = hi ? beg[3] : beg[2];
    int cB = hi ? (deg[3] < 32 ? deg[3] : 32) : (deg[2] < 32 ? deg[2] : 32);
    int idxB = (e31 < cB) ? csr[bB + e31] : n;

    // issue ALL gathers before any accumulate (up to 16 in flight)
    U4H B0[4], B1[4], B2[4], B3[4];
    #pragma unroll
    for (int r = 0; r < 4; ++r) {
        if (nr[0] > r) { int u = __shfl(idxA, r * 8 + g, 64);      B0[r].u = gin[(size_t)u * 8 + l]; }
        if (nr[1] > r) { int u = __shfl(idxA, 32 + r * 8 + g, 64); B1[r].u = gin[(size_t)u * 8 + l]; }
        if (nr[2] > r) { int u = __shfl(idxB, r * 8 + g, 64);      B2[r].u = gin[(size_t)u * 8 + l]; }
        if (nr[3] > r) { int u = __shfl(idxB, 32 + r * 8 + g, 64); B3[r].u = gin[(size_t)u * 8 + l]; }
    }

    __half2 z = __floats2half2_rn(0.f, 0.f);
    float acc0[8], acc1[8], acc2[8], acc3[8];
    ACCUM_NODE(0, B0, acc0)
    ACCUM_NODE(1, B1, acc1)
    ACCUM_NODE(2, B2, acc2)
    ACCUM_NODE(3, B3, acc3)

    // reduce across the 8 edge-subgroups (lane bits 3,4,5) in f32
    #pragma unroll
    for (int m = 8; m <= 32; m <<= 1) {
        #pragma unroll
        for (int jj = 0; jj < 8; ++jj) {
            acc0[jj] += __shfl_xor(acc0[jj], m, 64);
            acc1[jj] += __shfl_xor(acc1[jj], m, 64);
            acc2[jj] += __shfl_xor(acc2[jj], m, 64);
            acc3[jj] += __shfl_xor(acc3[jj], m, 64);
        }
    }

    float4 sa = make_float4(0.f, 0.f, 0.f, 0.f), sb = sa;
    if (do_pool) {
        const float4* s4 = (const float4*)s;
        sa = s4[2 * l]; sb = s4[2 * l + 1];
    }

    STORE_NODE(0, acc0)
    STORE_NODE(1, acc1)
    STORE_NODE(2, acc2)
    STORE_NODE(3, acc3)
}

// ---- deferred pooling epilogue ------------------------------------------
// out = sum_t sigmoid((g_t . s)/nv) * g_t / nv   over t=0..KHOPS
// (g_t = h_t * nv, with h_0 = features). One streaming pass, out written once.

__global__ void pool_epilogue(const uint4* __restrict__ gbase, size_t gstride,
                              const float* __restrict__ norm,
                              const float* __restrict__ s,
                              float4* __restrict__ out, int N) {
    int t0 = blockIdx.x * blockDim.x + threadIdx.x;
    int node = t0 >> 3;
    int l = t0 & 7;
    if (node >= N) return;          // uniform per 8-lane group
    float inv_nv = 1.0f / norm[node];
    const float4* s4 = (const float4*)s;
    float4 sa = s4[2 * l], sb = s4[2 * l + 1];
    float o[8] = {0.f, 0.f, 0.f, 0.f, 0.f, 0.f, 0.f, 0.f};
    for (int t = 0; t <= KHOPS; ++t) {
        U4H P; P.u = gbase[(size_t)t * gstride + (size_t)node * 8 + l];
        float2 a0 = __half22float2(P.h[0]), a1 = __half22float2(P.h[1]);
        float2 a2 = __half22float2(P.h[2]), a3 = __half22float2(P.h[3]);
        float gf[8] = {a0.x, a0.y, a1.x, a1.y, a2.x, a2.y, a3.x, a3.y};
        float dot = gf[0] * sa.x + gf[1] * sa.y + gf[2] * sa.z + gf[3] * sa.w
                  + gf[4] * sb.x + gf[5] * sb.y + gf[6] * sb.z + gf[7] * sb.w;
        #pragma unroll
        for (int m = 1; m <= 4; m <<= 1) dot += __shfl_xor(dot, m, 64);
        float sig = 1.0f / (1.0f + expf(-dot * inv_nv));
        float sc = sig * inv_nv;
        #pragma unroll
        for (int j = 0; j < 8; ++j) o[j] += sc * gf[j];
    }
    out[node * 16 + 2 * l]     = make_float4(o[0], o[1], o[2], o[3]);
    out[node * 16 + 2 * l + 1] = make_float4(o[4], o[5], o[6], o[7]);
}

// ---- launcher -----------------------------------------------------------

extern "C" void kernel_launch(void* const* d_in, const int* in_sizes, int n_in,
                              void* d_out, int out_size, void* d_ws, size_t ws_size,
                              hipStream_t stream) {
    const float* feat = (const float*)d_in[0];
    const float* s    = (const float*)d_in[1];
    const int*   src  = (const int*)d_in[2];
    const int*   dst  = (const int*)d_in[3];

    int N = in_sizes[0] / D;
    int E = in_sizes[2];
    int NR   = (N + RB - 1) / RB;          // 98 ranges  (<= NRMAX)
    int NBLK = (E + EB - 1) / EB;          // 782 edge blocks
    int M    = NR * NBLK;
    int nchA = (M + 1023) / 1024;

    // fixed workspace layout
    int*   offsets  = (int*)d_ws;                  // N+1
    int*   csr      = offsets + (N + 1);           // E
    float* norm     = (float*)(csr + E);           // N
    int*   countsA  = (int*)(norm + N);            // M
    int*   baseA    = countsA + M;                 // M
    int*   bsumA    = baseA + M;                   // nchA
    uintptr_t p = (uintptr_t)(bsumA + nchA);
    p = (p + 255) & ~(uintptr_t)255;
    uint4* gbase = (uint4*)p;                      // f16 rows: (N+1)*8 uint4/buffer
    size_t gstride = (size_t)(N + 1) * 8;          // uint4 per buffer (row N = zeros)

    // deferred pooling needs KHOPS+1 g buffers; fall back to 2-buffer ping-pong
    size_t fixed_bytes = (uintptr_t)gbase - (uintptr_t)d_ws;
    int deferred = (ws_size >= fixed_bytes + (size_t)(KHOPS + 1) * gstride * sizeof(uint4)) ? 1 : 0;

    // ebuf2 (E u32 = 6.4MB) aliases g buffer #1 (first written by the first
    // spmm hop, after range_build has consumed ebuf2)
    unsigned int* ebuf2 = (unsigned int*)(gbase + gstride);

    // multisplit CSR build (zero global atomics)
    countA<<<NBLK, 256, 0, stream>>>(dst, countsA, E, NR, NBLK);
    block_sums<<<nchA, 256, 0, stream>>>(countsA, bsumA, M);
    scan_bsums<<<1, 1024, 0, stream>>>(bsumA, nchA);
    gen_scan2<<<nchA, 1024, 0, stream>>>(countsA, bsumA, baseA, M);
    passA2<<<NBLK, 256, 0, stream>>>(src, dst, baseA, ebuf2, E, NR, NBLK);
    range_build<<<NR, RB, 0, stream>>>(ebuf2, baseA, offsets, norm, csr, N, E, NR, NBLK);

    float4* outp = (float4*)d_out;
    int nb_node8 = ((N + 1) * 8 + 255) / 256;      // MUST cover pad node N
    int nb_spmm  = (N + 16) / 16;                  // 16 nodes per block (covers pad)

    hop0<<<nb_node8, 256, 0, stream>>>((const float4*)feat, s, norm, gbase,
                                       outp, N, deferred ? 0 : 1);

    if (deferred) {
        for (int t = 0; t < KHOPS; ++t) {
            spmm_hop<<<nb_spmm, 256, 0, stream>>>(
                gbase + (size_t)t * gstride, offsets, csr, norm, s,
                gbase + (size_t)(t + 1) * gstride, outp, N, 0, 1);
        }
        pool_epilogue<<<nb_node8, 256, 0, stream>>>(gbase, gstride, norm, s, outp, N);
    } else {
        uint4* gin = gbase;
        uint4* gout = gbase + gstride;
        for (int t = 0; t < KHOPS; ++t) {
            spmm_hop<<<nb_spmm, 256, 0, stream>>>(
                gin, offsets, csr, norm, s, gout, outp, N, 1, (t < KHOPS - 1) ? 1 : 0);
            uint4* tmp = gin; gin = gout; gout = tmp;
        }
    }
}

// Round 4
// 508.396 us; speedup vs baseline: 1.2387x; 1.2387x over previous
//
#include <hip/hip_runtime.h>
#include <hip/hip_fp16.h>
#include <math.h>

#define D 64
#define RB 1024          // nodes per range (must match >>10 / &1023 below)
#define EB 2048          // edges per partition block
#define NRMAX 128        // static LDS sizing; NR = ceil(N/RB) must be <= NRMAX
#define KHOPS 10

// ---- helpers ------------------------------------------------------------

typedef union { uint4 u; __half2 h[4]; } U4H;

// ---- multisplit CSR build (no global atomics anywhere) ------------------

__global__ void countA(const int* __restrict__ dst, int* __restrict__ countsA_T,
                       int E, int NR, int NBLK) {
    __shared__ int hist[NRMAX];
    int t = threadIdx.x;
    for (int i = t; i < NR; i += 256) hist[i] = 0;
    __syncthreads();
    int base = blockIdx.x * EB + t;
    #pragma unroll
    for (int j = 0; j < EB / 256; ++j) {
        int e = base + j * 256;
        if (e < E) atomicAdd(&hist[dst[e] >> 10], 1);
    }
    __syncthreads();
    for (int i = t; i < NR; i += 256) countsA_T[i * NBLK + blockIdx.x] = hist[i];
}

__global__ void block_sums(const int* __restrict__ arr, int* __restrict__ bsum, int n) {
    int base = blockIdx.x * 1024;
    int t = threadIdx.x;
    int v = 0;
    #pragma unroll
    for (int j = 0; j < 4; ++j) {
        int i = base + t + j * 256;
        if (i < n) v += arr[i];
    }
    #pragma unroll
    for (int m = 32; m >= 1; m >>= 1) v += __shfl_xor(v, m, 64);
    __shared__ int ws[4];
    if ((t & 63) == 0) ws[t >> 6] = v;
    __syncthreads();
    if (t == 0) bsum[blockIdx.x] = ws[0] + ws[1] + ws[2] + ws[3];
}

__global__ void scan_bsums(int* __restrict__ bsum, int nb) {
    __shared__ int tmp[1024];
    int t = threadIdx.x;
    int v = (t < nb) ? bsum[t] : 0;
    tmp[t] = v;
    __syncthreads();
    for (int off = 1; off < 1024; off <<= 1) {
        int x = (t >= off) ? tmp[t - off] : 0;
        __syncthreads();
        tmp[t] += x;
        __syncthreads();
    }
    if (t < nb) bsum[t] = tmp[t] - v;
}

__global__ void gen_scan2(const int* __restrict__ arr, const int* __restrict__ bsum,
                          int* __restrict__ out, int n) {
    __shared__ int tmp[1024];
    int base = blockIdx.x * 1024;
    int t = threadIdx.x;
    int i = base + t;
    int v = (i < n) ? arr[i] : 0;
    tmp[t] = v;
    __syncthreads();
    for (int off = 1; off < 1024; off <<= 1) {
        int x = (t >= off) ? tmp[t - off] : 0;
        __syncthreads();
        tmp[t] += x;
        __syncthreads();
    }
    if (i < n) out[i] = bsum[blockIdx.x] + tmp[t] - v;
}

__global__ void passA2(const int* __restrict__ src, const int* __restrict__ dst,
                       const int* __restrict__ baseA, unsigned int* __restrict__ ebuf2,
                       int E, int NR, int NBLK) {
    __shared__ int cur[NRMAX];
    int t = threadIdx.x;
    for (int i = t; i < NR; i += 256) cur[i] = baseA[i * NBLK + blockIdx.x];
    __syncthreads();
    int base = blockIdx.x * EB + t;
    #pragma unroll
    for (int j = 0; j < EB / 256; ++j) {
        int e = base + j * 256;
        if (e < E) {
            int v = dst[e];
            int pos = atomicAdd(&cur[v >> 10], 1);
            ebuf2[pos] = (unsigned int)src[e] | ((unsigned int)(v & (RB - 1)) << 17);
        }
    }
}

__global__ void range_build(const unsigned int* __restrict__ ebuf2,
                            const int* __restrict__ baseA,
                            int* __restrict__ offsets, float* __restrict__ norm,
                            int* __restrict__ csr, int N, int E, int NR, int NBLK) {
    __shared__ int cnt[RB];
    __shared__ int sc[RB];
    int rg = blockIdx.x;
    int t = threadIdx.x;
    int r0 = baseA[rg * NBLK];
    int r1 = (rg + 1 < NR) ? baseA[(rg + 1) * NBLK] : E;
    cnt[t] = 0;
    __syncthreads();
    for (int i = r0 + t; i < r1; i += RB)
        atomicAdd(&cnt[ebuf2[i] >> 17], 1);
    __syncthreads();
    int v = cnt[t];
    sc[t] = v;
    __syncthreads();
    for (int off = 1; off < RB; off <<= 1) {
        int x = (t >= off) ? sc[t - off] : 0;
        __syncthreads();
        sc[t] += x;
        __syncthreads();
    }
    int excl = sc[t] - v;
    int node = rg * RB + t;
    if (node < N) {
        offsets[node] = r0 + excl;
        norm[node] = rsqrtf((float)(v > 1 ? v : 1));
    }
    if (rg == NR - 1 && t == 0) offsets[N] = E;
    __syncthreads();
    cnt[t] = r0 + excl;
    __syncthreads();
    for (int i = r0 + t; i < r1; i += RB) {
        unsigned int u = ebuf2[i];
        int pos = atomicAdd(&cnt[u >> 17], 1);
        csr[pos] = (int)(u & 0x1FFFFu);
    }
}

// ---- hop 0: g0 = f16(f*norm); if do_pool also out = sigmoid(f.s)*f ------
// 8 lanes per node, 8 dims (2 float4) per lane. Row N of g0 is the shared
// all-zero pad row that lets spmm_hop gather without per-lane masking.
// GRID MUST COVER (N+1)*8 THREADS so the pad row actually gets zeroed.

__global__ void hop0(const float4* __restrict__ feat, const float* __restrict__ s,
                     const float* __restrict__ norm, uint4* __restrict__ g0,
                     float4* __restrict__ out, int n, int do_pool) {
    int t = blockIdx.x * blockDim.x + threadIdx.x;
    int node = t >> 3;
    int l = t & 7;
    if (node > n) return;
    if (node == n) {                           // zero pad row
        g0[(size_t)n * 8 + l] = make_uint4(0u, 0u, 0u, 0u);
        return;
    }
    float4 f0 = feat[node * 16 + 2 * l];
    float4 f1 = feat[node * 16 + 2 * l + 1];
    float nv = norm[node];
    U4H P;
    P.h[0] = __floats2half2_rn(f0.x * nv, f0.y * nv);
    P.h[1] = __floats2half2_rn(f0.z * nv, f0.w * nv);
    P.h[2] = __floats2half2_rn(f1.x * nv, f1.y * nv);
    P.h[3] = __floats2half2_rn(f1.z * nv, f1.w * nv);
    g0[(size_t)node * 8 + l] = P.u;
    if (do_pool) {
        const float4* s4 = (const float4*)s;
        float4 a = s4[2 * l], b = s4[2 * l + 1];
        float dot = f0.x * a.x + f0.y * a.y + f0.z * a.z + f0.w * a.w
                  + f1.x * b.x + f1.y * b.y + f1.z * b.z + f1.w * b.w;
        #pragma unroll
        for (int m = 1; m <= 4; m <<= 1) dot += __shfl_xor(dot, m, 64);
        float sig = 1.0f / (1.0f + expf(-dot));
        out[node * 16 + 2 * l]     = make_float4(sig * f0.x, sig * f0.y, sig * f0.z, sig * f0.w);
        out[node * 16 + 2 * l + 1] = make_float4(sig * f1.x, sig * f1.y, sig * f1.z, sig * f1.w);
    }
}

// ---- hop t: gather-SpMM (f16 rows, packed-f16 accumulate) ---------------
// wave per node; lane = 8*g + l. The 4 row-gathers are UNCONDITIONAL and
// straight-line, pinned ahead of all consumes by sched_barrier(0): profiling
// showed VGPR_Count=20 on the previous versions, i.e. the compiler reused
// one gather buffer and serialized the loads (load->vmcnt(0)->consume x4,
// ~4 serial memory latencies per wave). Forcing all 4 buffers live yields
// vmcnt(3)-style pipelining: one exposed latency per wave. Invalid edge
// slots gather the all-zero pad row n (exact +0 in f16, bit-identical, and
// all dead lanes hit the same 2 hot cache lines -> near-free).

__global__ __launch_bounds__(256, 8)
void spmm_hop(const uint4* __restrict__ gin, const int* __restrict__ offsets,
              const int* __restrict__ csr, const float* __restrict__ norm,
              const float* __restrict__ s, uint4* __restrict__ gout,
              float4* __restrict__ out, int n, int do_pool, int write_g) {
    int lane = threadIdx.x & 63;
    int node = __builtin_amdgcn_readfirstlane(blockIdx.x * 4 + (threadIdx.x >> 6));
    if (node > n) return;            // wave-uniform exit
    int g = lane >> 3;
    int l = lane & 7;
    if (node == n) {                 // maintain zero pad row in gout
        if (write_g && g == 0) gout[(size_t)n * 8 + l] = make_uint4(0u, 0u, 0u, 0u);
        return;
    }
    int beg = offsets[node], end = offsets[node + 1];   // s_loads (node is SGPR)
    int deg = end - beg;
    int dcap = deg < 32 ? deg : 32;
    int idx = (lane < dcap) ? csr[beg + lane] : n;      // n = zero pad row

    // distribute indices, then issue all 4 gathers back-to-back
    int u0 = __shfl(idx, g,      64);
    int u1 = __shfl(idx, g + 8,  64);
    int u2 = __shfl(idx, g + 16, 64);
    int u3 = __shfl(idx, g + 24, 64);
    U4H A0, A1, A2, A3;
    A0.u = gin[(size_t)u0 * 8 + l];
    A1.u = gin[(size_t)u1 * 8 + l];
    A2.u = gin[(size_t)u2 * 8 + l];
    A3.u = gin[(size_t)u3 * 8 + l];
    __builtin_amdgcn_sched_barrier(0);   // loads stay above; consumes stay below

    __half2 ah0, ah1, ah2, ah3;
    ah0 = __hadd2(A0.h[0], A1.h[0]); ah1 = __hadd2(A0.h[1], A1.h[1]);
    ah2 = __hadd2(A0.h[2], A1.h[2]); ah3 = __hadd2(A0.h[3], A1.h[3]);
    ah0 = __hadd2(ah0, A2.h[0]);     ah1 = __hadd2(ah1, A2.h[1]);
    ah2 = __hadd2(ah2, A2.h[2]);     ah3 = __hadd2(ah3, A2.h[3]);
    ah0 = __hadd2(ah0, A3.h[0]);     ah1 = __hadd2(ah1, A3.h[1]);
    ah2 = __hadd2(ah2, A3.h[2]);     ah3 = __hadd2(ah3, A3.h[3]);

    float2 q0 = __half22float2(ah0), q1 = __half22float2(ah1);
    float2 q2 = __half22float2(ah2), q3 = __half22float2(ah3);
    float acc[8] = {q0.x, q0.y, q1.x, q1.y, q2.x, q2.y, q3.x, q3.y};

    for (int i = beg + 32 + g; i < end; i += 8) {   // deg>32: rare (P ~ 1e-4)
        U4H P; P.u = gin[(size_t)csr[i] * 8 + l];
        float2 a0 = __half22float2(P.h[0]), a1 = __half22float2(P.h[1]);
        float2 a2 = __half22float2(P.h[2]), a3 = __half22float2(P.h[3]);
        acc[0] += a0.x; acc[1] += a0.y; acc[2] += a1.x; acc[3] += a1.y;
        acc[4] += a2.x; acc[5] += a2.y; acc[6] += a3.x; acc[7] += a3.y;
    }

    // reduce across the 8 edge-subgroups (lane bits 3,4,5) in f32
    #pragma unroll
    for (int m = 8; m <= 32; m <<= 1) {
        #pragma unroll
        for (int jj = 0; jj < 8; ++jj) acc[jj] += __shfl_xor(acc[jj], m, 64);
    }

    float nv = norm[node];
    float h[8];
    #pragma unroll
    for (int jj = 0; jj < 8; ++jj) h[jj] = acc[jj] * nv;

    float sig = 0.f;
    if (do_pool) {                   // wave-uniform flag
        const float4* s4 = (const float4*)s;
        float4 a = s4[2 * l], b = s4[2 * l + 1];
        float dot = h[0] * a.x + h[1] * a.y + h[2] * a.z + h[3] * a.w
                  + h[4] * b.x + h[5] * b.y + h[6] * b.z + h[7] * b.w;
        #pragma unroll
        for (int m = 1; m <= 4; m <<= 1) dot += __shfl_xor(dot, m, 64);
        sig = 1.0f / (1.0f + expf(-dot));
    }

    if (g == 0) {
        if (write_g) {
            U4H P;
            P.h[0] = __floats2half2_rn(h[0] * nv, h[1] * nv);
            P.h[1] = __floats2half2_rn(h[2] * nv, h[3] * nv);
            P.h[2] = __floats2half2_rn(h[4] * nv, h[5] * nv);
            P.h[3] = __floats2half2_rn(h[6] * nv, h[7] * nv);
            gout[(size_t)node * 8 + l] = P.u;
        }
        if (do_pool) {
            float4 o0 = out[node * 16 + 2 * l];
            float4 o1 = out[node * 16 + 2 * l + 1];
            o0.x += sig * h[0]; o0.y += sig * h[1]; o0.z += sig * h[2]; o0.w += sig * h[3];
            o1.x += sig * h[4]; o1.y += sig * h[5]; o1.z += sig * h[6]; o1.w += sig * h[7];
            out[node * 16 + 2 * l]     = o0;
            out[node * 16 + 2 * l + 1] = o1;
        }
    }
}

// ---- deferred pooling epilogue ------------------------------------------
// out = sum_t sigmoid((g_t . s)/nv) * g_t / nv   over t=0..KHOPS
// (g_t = h_t * nv, with h_0 = features). One streaming pass, out written once.

__global__ void pool_epilogue(const uint4* __restrict__ gbase, size_t gstride,
                              const float* __restrict__ norm,
                              const float* __restrict__ s,
                              float4* __restrict__ out, int N) {
    int t0 = blockIdx.x * blockDim.x + threadIdx.x;
    int node = t0 >> 3;
    int l = t0 & 7;
    if (node >= N) return;          // uniform per 8-lane group
    float inv_nv = 1.0f / norm[node];
    const float4* s4 = (const float4*)s;
    float4 sa = s4[2 * l], sb = s4[2 * l + 1];
    float o[8] = {0.f, 0.f, 0.f, 0.f, 0.f, 0.f, 0.f, 0.f};
    for (int t = 0; t <= KHOPS; ++t) {
        U4H P; P.u = gbase[(size_t)t * gstride + (size_t)node * 8 + l];
        float2 a0 = __half22float2(P.h[0]), a1 = __half22float2(P.h[1]);
        float2 a2 = __half22float2(P.h[2]), a3 = __half22float2(P.h[3]);
        float gf[8] = {a0.x, a0.y, a1.x, a1.y, a2.x, a2.y, a3.x, a3.y};
        float dot = gf[0] * sa.x + gf[1] * sa.y + gf[2] * sa.z + gf[3] * sa.w
                  + gf[4] * sb.x + gf[5] * sb.y + gf[6] * sb.z + gf[7] * sb.w;
        #pragma unroll
        for (int m = 1; m <= 4; m <<= 1) dot += __shfl_xor(dot, m, 64);
        float sig = 1.0f / (1.0f + expf(-dot * inv_nv));
        float sc = sig * inv_nv;
        #pragma unroll
        for (int j = 0; j < 8; ++j) o[j] += sc * gf[j];
    }
    out[node * 16 + 2 * l]     = make_float4(o[0], o[1], o[2], o[3]);
    out[node * 16 + 2 * l + 1] = make_float4(o[4], o[5], o[6], o[7]);
}

// ---- launcher -----------------------------------------------------------

extern "C" void kernel_launch(void* const* d_in, const int* in_sizes, int n_in,
                              void* d_out, int out_size, void* d_ws, size_t ws_size,
                              hipStream_t stream) {
    const float* feat = (const float*)d_in[0];
    const float* s    = (const float*)d_in[1];
    const int*   src  = (const int*)d_in[2];
    const int*   dst  = (const int*)d_in[3];

    int N = in_sizes[0] / D;
    int E = in_sizes[2];
    int NR   = (N + RB - 1) / RB;          // 98 ranges  (<= NRMAX)
    int NBLK = (E + EB - 1) / EB;          // 782 edge blocks
    int M    = NR * NBLK;
    int nchA = (M + 1023) / 1024;

    // fixed workspace layout
    int*   offsets  = (int*)d_ws;                  // N+1
    int*   csr      = offsets + (N + 1);           // E
    float* norm     = (float*)(csr + E);           // N
    int*   countsA  = (int*)(norm + N);            // M
    int*   baseA    = countsA + M;                 // M
    int*   bsumA    = baseA + M;                   // nchA
    uintptr_t p = (uintptr_t)(bsumA + nchA);
    p = (p + 255) & ~(uintptr_t)255;
    uint4* gbase = (uint4*)p;                      // f16 rows: (N+1)*8 uint4/buffer
    size_t gstride = (size_t)(N + 1) * 8;          // uint4 per buffer (row N = zeros)

    // deferred pooling needs KHOPS+1 g buffers; fall back to 2-buffer ping-pong
    size_t fixed_bytes = (uintptr_t)gbase - (uintptr_t)d_ws;
    int deferred = (ws_size >= fixed_bytes + (size_t)(KHOPS + 1) * gstride * sizeof(uint4)) ? 1 : 0;

    // ebuf2 (E u32 = 6.4MB) aliases g buffer #1 (first written by the first
    // spmm hop, after range_build has consumed ebuf2)
    unsigned int* ebuf2 = (unsigned int*)(gbase + gstride);

    // multisplit CSR build (zero global atomics)
    countA<<<NBLK, 256, 0, stream>>>(dst, countsA, E, NR, NBLK);
    block_sums<<<nchA, 256, 0, stream>>>(countsA, bsumA, M);
    scan_bsums<<<1, 1024, 0, stream>>>(bsumA, nchA);
    gen_scan2<<<nchA, 1024, 0, stream>>>(countsA, bsumA, baseA, M);
    passA2<<<NBLK, 256, 0, stream>>>(src, dst, baseA, ebuf2, E, NR, NBLK);
    range_build<<<NR, RB, 0, stream>>>(ebuf2, baseA, offsets, norm, csr, N, E, NR, NBLK);

    float4* outp = (float4*)d_out;
    int nb_node8 = ((N + 1) * 8 + 255) / 256;      // MUST cover pad node N
    int nb_spmm  = (N + 4) / 4;                    // +1 node for pad row

    hop0<<<nb_node8, 256, 0, stream>>>((const float4*)feat, s, norm, gbase,
                                       outp, N, deferred ? 0 : 1);

    if (deferred) {
        for (int t = 0; t < KHOPS; ++t) {
            spmm_hop<<<nb_spmm, 256, 0, stream>>>(
                gbase + (size_t)t * gstride, offsets, csr, norm, s,
                gbase + (size_t)(t + 1) * gstride, outp, N, 0, 1);
        }
        pool_epilogue<<<nb_node8, 256, 0, stream>>>(gbase, gstride, norm, s, outp, N);
    } else {
        uint4* gin = gbase;
        uint4* gout = gbase + gstride;
        for (int t = 0; t < KHOPS; ++t) {
            spmm_hop<<<nb_spmm, 256, 0, stream>>>(
                gin, offsets, csr, norm, s, gout, outp, N, 1, (t < KHOPS - 1) ? 1 : 0);
            uint4* tmp = gin; gin = gout; gout = tmp;
        }
    }
}